// Round 7
// baseline (538.786 us; speedup 1.0000x reference)
//
#include <hip/hip_runtime.h>
#include <hip/hip_cooperative_groups.h>
#include <math.h>

namespace cg = cooperative_groups;

#define NPTS 4096
#define NB 4
#define EPSF 1e-6f

// ============================================================================
// Shared device bodies (used by both the fused cooperative kernel and the
// 5-kernel fallback). All arithmetic is character-identical to the R5-proven
// kernels (absmax 0.0).
// ============================================================================

__device__ __forceinline__ void gravity_align_rt(
    const float* __restrict__ g_p, const float* __restrict__ g_q,
    const float* sums, int b, float* R_out, float* t_out) {
    // gravity_align(g_p[b], g_q[b]) exactly per reference
    float gpx = g_p[3 * b + 0], gpy = g_p[3 * b + 1], gpz = g_p[3 * b + 2];
    float gqx = g_q[3 * b + 0], gqy = g_q[3 * b + 1], gqz = g_q[3 * b + 2];
    float nu = sqrtf(gpx * gpx + gpy * gpy + gpz * gpz);
    float du = fmaxf(nu, EPSF);
    float ux = gpx / du, uy = gpy / du, uz = gpz / du;
    float nv = sqrtf(gqx * gqx + gqy * gqy + gqz * gqz);
    float dv = fmaxf(nv, EPSF);
    float vx = gqx / dv, vy = gqy / dv, vz = gqz / dv;

    float ax = uy * vz - uz * vy;
    float ay = uz * vx - ux * vz;
    float az = ux * vy - uy * vx;
    float an = sqrtf(ax * ax + ay * ay + az * az);
    float dot = ux * vx + uy * vy + uz * vz;
    dot = fminf(1.0f, fmaxf(-1.0f, dot));
    bool parallel = (an < 1e-6f);

    float kx = ax / (an + EPSF), ky = ay / (an + EPSF), kz = az / (an + EPSF);
    float theta = acosf(dot);
    float st = sinf(theta), ct = cosf(theta);

    float K[9] = {0.f, -kz, ky,  kz, 0.f, -kx,  -ky, kx, 0.f};
    float KK[9];
    for (int i = 0; i < 3; ++i)
        for (int j = 0; j < 3; ++j) {
            float s2 = 0.f;
            for (int l = 0; l < 3; ++l) s2 += K[i * 3 + l] * K[l * 3 + j];
            KK[i * 3 + j] = s2;
        }
    float R[9];
    for (int i = 0; i < 9; ++i) {
        float I = (i == 0 || i == 4 || i == 8) ? 1.f : 0.f;
        R[i] = I + st * K[i] + (1.f - ct) * KK[i];
    }
    if (parallel) {
        if (dot < 0.f) {
            float bx, by, bz;
            if (fabsf(ux) < 0.9f) { bx = 1.f; by = 0.f; bz = 0.f; }
            else                  { bx = 0.f; by = 1.f; bz = 0.f; }
            float cx = uy * bz - uz * by;
            float cy = uz * bx - ux * bz;
            float cz = ux * by - uy * bx;
            float cn = sqrtf(cx * cx + cy * cy + cz * cz);
            float cd = fmaxf(cn, EPSF);
            cx /= cd; cy /= cd; cz /= cd;
            float K2[9] = {0.f, -cz, cy,  cz, 0.f, -cx,  -cy, cx, 0.f};
            float K2K2[9];
            for (int i = 0; i < 3; ++i)
                for (int j = 0; j < 3; ++j) {
                    float s2 = 0.f;
                    for (int l = 0; l < 3; ++l) s2 += K2[i * 3 + l] * K2[l * 3 + j];
                    K2K2[i * 3 + j] = s2;
                }
            for (int i = 0; i < 9; ++i) {
                float I = (i == 0 || i == 4 || i == 8) ? 1.f : 0.f;
                R[i] = I + 2.f * K2K2[i];
            }
        } else if (dot > 0.f) {
            for (int i = 0; i < 9; ++i) R[i] = (i == 0 || i == 4 || i == 8) ? 1.f : 0.f;
        }
    }
    float ms0 = sums[0] / (float)NPTS, ms1 = sums[1] / (float)NPTS, ms2 = sums[2] / (float)NPTS;
    float mt0 = sums[3] / (float)NPTS, mt1 = sums[4] / (float)NPTS, mt2 = sums[5] / (float)NPTS;
    for (int i = 0; i < 9; ++i) R_out[i] = R[i];
    t_out[0] = mt0 - (R[0] * ms0 + R[1] * ms1 + R[2] * ms2);
    t_out[1] = mt1 - (R[3] * ms0 + R[4] * ms1 + R[5] * ms2);
    t_out[2] = mt2 - (R[6] * ms0 + R[7] * ms1 + R[8] * ms2);
}

// ============================================================================
// Fused cooperative kernel. Grid (64, NB, 2) x 1024 thr = 512 blocks =
// 2 blocks/CU co-resident. Static LDS EXACTLY 64 KB: P0's reduction scratch
// is ALIASED into stage4 (R6 lesson: stage4 + separate red[] = 66.6 KB >
// 64 KB static limit -> launch silently failed).
// ============================================================================
__global__ __launch_bounds__(1024, 8) void mega(
    const float* __restrict__ src, const float* __restrict__ tgt,
    const float* __restrict__ src_n, const float* __restrict__ tgt_n,
    const float* __restrict__ g_p, const float* __restrict__ g_q,
    const float* __restrict__ k_p, const float* __restrict__ k_q,
    float4* __restrict__ p4, float4* __restrict__ q4,
    float4* __restrict__ snr4, float4* __restrict__ tn4,
    float* __restrict__ nnp, int* __restrict__ idxp,
    float* __restrict__ nnq, int* __restrict__ idxq,
    float* __restrict__ tau, float* __restrict__ out)
{
    cg::grid_group grid = cg::this_grid();
    const int tid = threadIdx.x;
    const int flat = blockIdx.x + 64 * blockIdx.y + 256 * blockIdx.z;

    __shared__ float4 stage4[NPTS];   // 64 KB, reused by every phase
    float* stagef = (float*)stage4;

    // ================= P0: means + R/t + pack (blocks 0..3) =============
    if (flat < NB) {
        const int b = flat;
        const float* S  = src   + (size_t)b * 3 * NPTS;
        const float* T  = tgt   + (size_t)b * 3 * NPTS;
        const float* SN = src_n + (size_t)b * 3 * NPTS;
        const float* TN = tgt_n + (size_t)b * 3 * NPTS;

        // LDS scratch aliased into stage4 (P0 doesn't use the stage)
        float* red  = stagef;        // 256 floats
        float* sums = stagef + 256;  // 6
        float* Rg   = stagef + 262;  // 9
        float* tc   = stagef + 271;  // 3

        // bit-exact 256-thread accumulation (guarded work, FULL-block barriers)
        float acc[6] = {0.f, 0.f, 0.f, 0.f, 0.f, 0.f};
        if (tid < 256) {
            for (int n = tid; n < NPTS; n += 256) {
                acc[0] += S[n]; acc[1] += S[NPTS + n]; acc[2] += S[2 * NPTS + n];
                acc[3] += T[n]; acc[4] += T[NPTS + n]; acc[5] += T[2 * NPTS + n];
            }
        }
        for (int c = 0; c < 6; ++c) {
            if (tid < 256) red[tid] = acc[c];
            __syncthreads();
            for (int s = 128; s > 0; s >>= 1) {
                if (tid < s) red[tid] += red[tid + s];
                __syncthreads();
            }
            if (tid == 0) sums[c] = red[0];
            __syncthreads();
        }

        if (tid == 0) gravity_align_rt(g_p, g_q, sums, b, Rg, tc);
        __syncthreads();

        const float R0 = Rg[0], R1 = Rg[1], R2 = Rg[2];
        const float R3 = Rg[3], R4 = Rg[4], R5 = Rg[5];
        const float R6 = Rg[6], R7 = Rg[7], R8 = Rg[8];
        const float t0 = tc[0], t1 = tc[1], t2 = tc[2];

        for (int n = tid; n < NPTS; n += 1024) {
            float s0 = S[n], s1 = S[NPTS + n], s2 = S[2 * NPTS + n];
            float p0 = R0 * s0 + R1 * s1 + R2 * s2 + t0;
            float p1 = R3 * s0 + R4 * s1 + R5 * s2 + t1;
            float p2 = R6 * s0 + R7 * s1 + R8 * s2 + t2;
            p4[b * NPTS + n] = make_float4(p0, p1, p2, p0 * p0 + p1 * p1 + p2 * p2);

            float q0 = T[n], q1 = T[NPTS + n], q2 = T[2 * NPTS + n];
            q4[b * NPTS + n] = make_float4(q0, q1, q2, q0 * q0 + q1 * q1 + q2 * q2);

            float a0 = SN[n], a1 = SN[NPTS + n], a2 = SN[2 * NPTS + n];
            snr4[b * NPTS + n] = make_float4(R0 * a0 + R1 * a1 + R2 * a2,
                                             R3 * a0 + R4 * a1 + R5 * a2,
                                             R6 * a0 + R7 * a1 + R8 * a2, 0.f);
            float c0 = TN[n], c1 = TN[NPTS + n], c2 = TN[2 * NPTS + n];
            tn4[b * NPTS + n] = make_float4(c0, c1, c2, 0.f);
        }
        __syncthreads();
    }
    __threadfence();
    grid.sync();

    // ================= PA: NN both directions (R5 k1 verbatim) ==========
    {
        const int b = blockIdx.y;
        const int z = blockIdx.z;
        const float4* own = z ? q4 : p4;
        const float4* oth = z ? p4 : q4;
        float* nn = z ? nnq : nnp;
        int* idx = z ? idxq : idxp;

        for (int i = tid; i < NPTS; i += 1024) {
            float4 v = oth[b * NPTS + i];
            v.w *= -0.5f;
            stage4[i] = v;
        }

        const int nl = tid & 63;
        const int stripe = tid >> 6;          // 0..15, each scans 256 points
        const int n = blockIdx.x * 64 + nl;
        const float4 p = own[b * NPTS + n];
        __syncthreads();

        const int m0 = stripe << 8;
        float best = -3.4e38f;
        int bi = m0;
        #pragma unroll 8
        for (int m = m0; m < m0 + 256; ++m) {
            float4 q = stage4[m];
            float s = fmaf(p.x, q.x, fmaf(p.y, q.y, fmaf(p.z, q.z, q.w)));
            if (s > best) { best = s; bi = m; }
        }
        __syncthreads();

        float* combd = (float*)stage4;
        int* combi = (int*)(combd + 1024);
        combd[tid] = best;
        combi[tid] = bi;
        __syncthreads();
        if (stripe == 0) {
            for (int s2 = 1; s2 < 16; ++s2) {
                float d2 = combd[s2 * 64 + nl];
                int i2 = combi[s2 * 64 + nl];
                if (d2 > best) { best = d2; bi = i2; }  // ties: lower m wins
            }
            float d = fmaf(-2.0f, best, p.w);
            nn[b * NPTS + n] = sqrtf(fmaxf(d, 0.f) + EPSF);
            idx[b * NPTS + n] = bi;
        }
        __syncthreads();
    }
    __threadfence();
    grid.sync();

    // ================= PB: tau rank-count select (R5 k2 verbatim) =======
    {
        const int b = blockIdx.y;
        const int side = blockIdx.z;
        const float* a = (side ? nnq : nnp) + b * NPTS;
        for (int i = tid; i < NPTS; i += 1024) stagef[i] = a[i];

        const int nl = tid & 63;
        const int stripe = tid >> 6;
        const int n = blockIdx.x * 64 + nl;
        __syncthreads();

        const float x = stagef[n];
        int less = 0, eq = 0;
        const int m0 = stripe << 8;
        #pragma unroll 8
        for (int m = m0; m < m0 + 256; ++m) {
            float o = stagef[m];  // broadcast read, conflict-free
            less += (o < x) ? 1 : 0;
            eq   += (o == x) ? 1 : 0;
        }
        __syncthreads();

        int* cl = (int*)stagef;
        int* ce = cl + 1024;
        cl[tid] = less;
        ce[tid] = eq;
        __syncthreads();
        if (stripe == 0) {
            for (int s2 = 1; s2 < 16; ++s2) {
                less += cl[s2 * 64 + nl];
                eq   += ce[s2 * 64 + nl];
            }
            if (less <= 2047 && 2047 < less + eq)
                tau[side * NB + b] = 3.0f * x;  // all winners bit-identical
        }
    }
    __threadfence();
    grid.sync();

    // ================= PC: incidence weights (R5 k3 arithmetic) =========
    if (flat < 32) {
        const int e = flat * 1024 + tid;      // e == z*16384 + b*4096 + n
        const int z = e >> 14;
        const int b = (e >> 12) & 3;
        const int n = e & (NPTS - 1);
        const float gx = g_q[3 * b + 0], gy = g_q[3 * b + 1], gz = g_q[3 * b + 2];
        const float kp = k_p[b], kq = k_q[b];
        const float keff = kp * kq / (kp + kq + EPSF);

        if (z == 0) {
            float4 sn = snr4[b * NPTS + n];
            float inc = sn.x * gx + sn.y * gy + sn.z * gz;
            int j = idxp[b * NPTS + n];
            float4 tn = tn4[b * NPTS + j];
            float incr = tn.x * gx + tn.y * gy + tn.z * gz;
            float diff = inc - incr;
            float arg = 9.0f - keff * diff * diff;
            float sig = 1.f / (1.f + expf(-arg));
            float geom = (nnp[b * NPTS + n] <= tau[b]) ? 1.f : 0.f;
            out[e] = sig * geom;
        } else {
            float4 tn = tn4[b * NPTS + n];
            float inc = tn.x * gx + tn.y * gy + tn.z * gz;
            int j = idxq[b * NPTS + n];
            float4 sn = snr4[b * NPTS + j];
            float incr = sn.x * gx + sn.y * gy + sn.z * gz;
            float diff = inc - incr;
            float arg = 9.0f - keff * diff * diff;
            float sig = 1.f / (1.f + expf(-arg));
            float geom = (nnq[b * NPTS + n] <= tau[NB + b]) ? 1.f : 0.f;
            out[e] = sig * geom;
        }
    }
}

// ============================================================================
// Fallback path: the R5-proven 5-kernel pipeline (verbatim).
// ============================================================================

__global__ void k0a_rt(const float* __restrict__ src, const float* __restrict__ tgt,
                       const float* __restrict__ g_p, const float* __restrict__ g_q,
                       float* __restrict__ Rt) {
    const int b = blockIdx.x;
    const int tid = threadIdx.x;
    const float* S = src + (size_t)b * 3 * NPTS;
    const float* T = tgt + (size_t)b * 3 * NPTS;

    float acc[6] = {0.f, 0.f, 0.f, 0.f, 0.f, 0.f};
    for (int n = tid; n < NPTS; n += 256) {
        acc[0] += S[n]; acc[1] += S[NPTS + n]; acc[2] += S[2 * NPTS + n];
        acc[3] += T[n]; acc[4] += T[NPTS + n]; acc[5] += T[2 * NPTS + n];
    }
    __shared__ float red[256];
    __shared__ float sums[6];
    for (int c = 0; c < 6; ++c) {
        red[tid] = acc[c];
        __syncthreads();
        for (int s = 128; s > 0; s >>= 1) {
            if (tid < s) red[tid] += red[tid + s];
            __syncthreads();
        }
        if (tid == 0) sums[c] = red[0];
        __syncthreads();
    }
    if (tid == 0) {
        float Rg[9], tc[3];
        gravity_align_rt(g_p, g_q, sums, b, Rg, tc);
        for (int i = 0; i < 9; ++i) Rt[b * 16 + i] = Rg[i];
        Rt[b * 16 + 9]  = tc[0];
        Rt[b * 16 + 10] = tc[1];
        Rt[b * 16 + 11] = tc[2];
    }
}

__global__ void k0b_pack(const float* __restrict__ src, const float* __restrict__ tgt,
                         const float* __restrict__ src_n, const float* __restrict__ tgt_n,
                         const float* __restrict__ Rt,
                         float4* __restrict__ p4, float4* __restrict__ q4,
                         float4* __restrict__ snr4, float4* __restrict__ tn4) {
    const int b = blockIdx.y;
    const float* S  = src   + (size_t)b * 3 * NPTS;
    const float* T  = tgt   + (size_t)b * 3 * NPTS;
    const float* SN = src_n + (size_t)b * 3 * NPTS;
    const float* TN = tgt_n + (size_t)b * 3 * NPTS;
    const float R0 = Rt[b*16+0], R1 = Rt[b*16+1], R2 = Rt[b*16+2];
    const float R3 = Rt[b*16+3], R4 = Rt[b*16+4], R5 = Rt[b*16+5];
    const float R6 = Rt[b*16+6], R7 = Rt[b*16+7], R8 = Rt[b*16+8];
    const float t0 = Rt[b*16+9], t1 = Rt[b*16+10], t2 = Rt[b*16+11];

    const int n0 = blockIdx.x * 512 + threadIdx.x;
    #pragma unroll
    for (int w = 0; w < 2; ++w) {
        const int n = n0 + w * 256;
        float s0 = S[n], s1 = S[NPTS + n], s2 = S[2 * NPTS + n];
        float p0 = R0 * s0 + R1 * s1 + R2 * s2 + t0;
        float p1 = R3 * s0 + R4 * s1 + R5 * s2 + t1;
        float p2 = R6 * s0 + R7 * s1 + R8 * s2 + t2;
        p4[b * NPTS + n] = make_float4(p0, p1, p2, p0 * p0 + p1 * p1 + p2 * p2);

        float q0 = T[n], q1 = T[NPTS + n], q2 = T[2 * NPTS + n];
        q4[b * NPTS + n] = make_float4(q0, q1, q2, q0 * q0 + q1 * q1 + q2 * q2);

        float a0 = SN[n], a1 = SN[NPTS + n], a2 = SN[2 * NPTS + n];
        snr4[b * NPTS + n] = make_float4(R0 * a0 + R1 * a1 + R2 * a2,
                                         R3 * a0 + R4 * a1 + R5 * a2,
                                         R6 * a0 + R7 * a1 + R8 * a2, 0.f);
        float c0 = TN[n], c1 = TN[NPTS + n], c2 = TN[2 * NPTS + n];
        tn4[b * NPTS + n] = make_float4(c0, c1, c2, 0.f);
    }
}

__global__ void k1_nn(const float4* __restrict__ p4, const float4* __restrict__ q4,
                      float* __restrict__ nnp, int* __restrict__ idxp,
                      float* __restrict__ nnq, int* __restrict__ idxq) {
    const int b = blockIdx.y;
    const int z = blockIdx.z;
    const float4* own = z ? q4 : p4;
    const float4* oth = z ? p4 : q4;
    float* nn = z ? nnq : nnp;
    int* idx = z ? idxq : idxp;

    __shared__ float4 stage[NPTS];  // 64 KB
    const int tid = threadIdx.x;
    for (int i = tid; i < NPTS; i += 1024) {
        float4 v = oth[b * NPTS + i];
        v.w *= -0.5f;
        stage[i] = v;
    }

    const int nl = tid & 63;
    const int stripe = tid >> 6;
    const int n = blockIdx.x * 64 + nl;
    const float4 p = own[b * NPTS + n];
    __syncthreads();

    const int m0 = stripe << 8;
    float best = -3.4e38f;
    int bi = m0;
    #pragma unroll 8
    for (int m = m0; m < m0 + 256; ++m) {
        float4 q = stage[m];
        float s = fmaf(p.x, q.x, fmaf(p.y, q.y, fmaf(p.z, q.z, q.w)));
        if (s > best) { best = s; bi = m; }
    }
    __syncthreads();

    float* combd = (float*)stage;
    int* combi = (int*)(combd + 1024);
    combd[tid] = best;
    combi[tid] = bi;
    __syncthreads();
    if (stripe == 0) {
        for (int s2 = 1; s2 < 16; ++s2) {
            float d2 = combd[s2 * 64 + nl];
            int i2 = combi[s2 * 64 + nl];
            if (d2 > best) { best = d2; bi = i2; }
        }
        float d = fmaf(-2.0f, best, p.w);
        nn[b * NPTS + n] = sqrtf(fmaxf(d, 0.f) + EPSF);
        idx[b * NPTS + n] = bi;
    }
}

__global__ void k2_tau(const float* __restrict__ nnp, const float* __restrict__ nnq,
                       float* __restrict__ tau) {
    const int b = blockIdx.y;
    const int side = blockIdx.z;
    const float* a = (side ? nnq : nnp) + b * NPTS;
    __shared__ float stage[NPTS];  // 16 KB
    const int tid = threadIdx.x;
    for (int i = tid; i < NPTS; i += 1024) stage[i] = a[i];

    const int nl = tid & 63;
    const int stripe = tid >> 6;
    const int n = blockIdx.x * 64 + nl;
    __syncthreads();

    const float x = stage[n];
    int less = 0, eq = 0;
    const int m0 = stripe << 8;
    #pragma unroll 8
    for (int m = m0; m < m0 + 256; ++m) {
        float o = stage[m];
        less += (o < x) ? 1 : 0;
        eq   += (o == x) ? 1 : 0;
    }
    __syncthreads();

    int* cl = (int*)stage;
    int* ce = cl + 1024;
    cl[tid] = less;
    ce[tid] = eq;
    __syncthreads();
    if (stripe == 0) {
        for (int s2 = 1; s2 < 16; ++s2) {
            less += cl[s2 * 64 + nl];
            eq   += ce[s2 * 64 + nl];
        }
        if (less <= 2047 && 2047 < less + eq)
            tau[side * NB + b] = 3.0f * x;
    }
}

__global__ void k3_w(const float4* __restrict__ snr4, const float4* __restrict__ tn4,
                     const int* __restrict__ idxp, const int* __restrict__ idxq,
                     const float* __restrict__ nnp, const float* __restrict__ nnq,
                     const float* __restrict__ tau,
                     const float* __restrict__ g_q, const float* __restrict__ k_p,
                     const float* __restrict__ k_q, float* __restrict__ out) {
    const int b = blockIdx.y;
    const int z = blockIdx.z;
    const int n = blockIdx.x * 256 + threadIdx.x;
    const float gx = g_q[3 * b + 0], gy = g_q[3 * b + 1], gz = g_q[3 * b + 2];
    const float kp = k_p[b], kq = k_q[b];
    const float keff = kp * kq / (kp + kq + EPSF);

    if (z == 0) {
        float4 sn = snr4[b * NPTS + n];
        float inc = sn.x * gx + sn.y * gy + sn.z * gz;
        int j = idxp[b * NPTS + n];
        float4 tn = tn4[b * NPTS + j];
        float incr = tn.x * gx + tn.y * gy + tn.z * gz;
        float diff = inc - incr;
        float arg = 9.0f - keff * diff * diff;
        float sig = 1.f / (1.f + expf(-arg));
        float geom = (nnp[b * NPTS + n] <= tau[b]) ? 1.f : 0.f;
        out[b * NPTS + n] = sig * geom;
    } else {
        float4 tn = tn4[b * NPTS + n];
        float inc = tn.x * gx + tn.y * gy + tn.z * gz;
        int j = idxq[b * NPTS + n];
        float4 sn = snr4[b * NPTS + j];
        float incr = sn.x * gx + sn.y * gy + sn.z * gz;
        float diff = inc - incr;
        float arg = 9.0f - keff * diff * diff;
        float sig = 1.f / (1.f + expf(-arg));
        float geom = (nnq[b * NPTS + n] <= tau[NB + b]) ? 1.f : 0.f;
        out[NB * NPTS + b * NPTS + n] = sig * geom;
    }
}

extern "C" void kernel_launch(void* const* d_in, const int* in_sizes, int n_in,
                              void* d_out, int out_size, void* d_ws, size_t ws_size,
                              hipStream_t stream) {
    const float* src   = (const float*)d_in[0];
    const float* tgt   = (const float*)d_in[1];
    const float* src_n = (const float*)d_in[2];
    const float* tgt_n = (const float*)d_in[3];
    const float* g_p   = (const float*)d_in[4];
    const float* k_p   = (const float*)d_in[5];
    const float* g_q   = (const float*)d_in[6];
    const float* k_q   = (const float*)d_in[7];
    float* out = (float*)d_out;

    const int BN = NB * NPTS;
    float4* p4   = (float4*)d_ws;
    float4* q4   = p4 + BN;
    float4* snr4 = q4 + BN;
    float4* tn4  = snr4 + BN;
    float* nnp = (float*)(tn4 + BN);
    float* nnq = nnp + BN;
    int* idxp = (int*)(nnq + BN);
    int* idxq = idxp + BN;
    float* tau = (float*)(idxq + BN);   // 2*NB floats
    float* Rt  = tau + 2 * NB;          // NB*16 floats

    void* args[] = {
        (void*)&src, (void*)&tgt, (void*)&src_n, (void*)&tgt_n,
        (void*)&g_p, (void*)&g_q, (void*)&k_p, (void*)&k_q,
        (void*)&p4, (void*)&q4, (void*)&snr4, (void*)&tn4,
        (void*)&nnp, (void*)&idxp, (void*)&nnq, (void*)&idxq,
        (void*)&tau, (void*)&out
    };
    hipError_t err = hipLaunchCooperativeKernel((void*)mega,
                                                dim3(NPTS / 64, NB, 2), dim3(1024),
                                                args, 0, stream);
    if (err != hipSuccess) {
        // Proven R5 5-kernel path (60.3 us, absmax 0.0).
        k0a_rt<<<dim3(NB), dim3(256), 0, stream>>>(src, tgt, g_p, g_q, Rt);
        k0b_pack<<<dim3(8, NB), dim3(256), 0, stream>>>(src, tgt, src_n, tgt_n, Rt,
                                                        p4, q4, snr4, tn4);
        k1_nn<<<dim3(NPTS / 64, NB, 2), dim3(1024), 0, stream>>>(p4, q4, nnp, idxp, nnq, idxq);
        k2_tau<<<dim3(NPTS / 64, NB, 2), dim3(1024), 0, stream>>>(nnp, nnq, tau);
        k3_w<<<dim3(NPTS / 256, NB, 2), dim3(256), 0, stream>>>(snr4, tn4, idxp, idxq,
                                                                nnp, nnq, tau,
                                                                g_q, k_p, k_q, out);
    }
}

// Round 8
// 67.574 us; speedup vs baseline: 7.9733x; 7.9733x over previous
//
#include <hip/hip_runtime.h>
#include <math.h>

#define NPTS 4096
#define NB 4
#define EPSF 1e-6f

// ============================================================================
// gravity_align + t_center (exact reference arithmetic; proven bit-exact
// R1-R7). Called by thread 0 of k0's per-batch block.
// ============================================================================
__device__ __forceinline__ void gravity_align_rt(
    const float* __restrict__ g_p, const float* __restrict__ g_q,
    const float* sums, int b, float* R_out, float* t_out) {
    float gpx = g_p[3 * b + 0], gpy = g_p[3 * b + 1], gpz = g_p[3 * b + 2];
    float gqx = g_q[3 * b + 0], gqy = g_q[3 * b + 1], gqz = g_q[3 * b + 2];
    float nu = sqrtf(gpx * gpx + gpy * gpy + gpz * gpz);
    float du = fmaxf(nu, EPSF);
    float ux = gpx / du, uy = gpy / du, uz = gpz / du;
    float nv = sqrtf(gqx * gqx + gqy * gqy + gqz * gqz);
    float dv = fmaxf(nv, EPSF);
    float vx = gqx / dv, vy = gqy / dv, vz = gqz / dv;

    float ax = uy * vz - uz * vy;
    float ay = uz * vx - ux * vz;
    float az = ux * vy - uy * vx;
    float an = sqrtf(ax * ax + ay * ay + az * az);
    float dot = ux * vx + uy * vy + uz * vz;
    dot = fminf(1.0f, fmaxf(-1.0f, dot));
    bool parallel = (an < 1e-6f);

    float kx = ax / (an + EPSF), ky = ay / (an + EPSF), kz = az / (an + EPSF);
    float theta = acosf(dot);
    float st = sinf(theta), ct = cosf(theta);

    float K[9] = {0.f, -kz, ky,  kz, 0.f, -kx,  -ky, kx, 0.f};
    float KK[9];
    for (int i = 0; i < 3; ++i)
        for (int j = 0; j < 3; ++j) {
            float s2 = 0.f;
            for (int l = 0; l < 3; ++l) s2 += K[i * 3 + l] * K[l * 3 + j];
            KK[i * 3 + j] = s2;
        }
    float R[9];
    for (int i = 0; i < 9; ++i) {
        float I = (i == 0 || i == 4 || i == 8) ? 1.f : 0.f;
        R[i] = I + st * K[i] + (1.f - ct) * KK[i];
    }
    if (parallel) {
        if (dot < 0.f) {
            float bx, by, bz;
            if (fabsf(ux) < 0.9f) { bx = 1.f; by = 0.f; bz = 0.f; }
            else                  { bx = 0.f; by = 1.f; bz = 0.f; }
            float cx = uy * bz - uz * by;
            float cy = uz * bx - ux * bz;
            float cz = ux * by - uy * bx;
            float cn = sqrtf(cx * cx + cy * cy + cz * cz);
            float cd = fmaxf(cn, EPSF);
            cx /= cd; cy /= cd; cz /= cd;
            float K2[9] = {0.f, -cz, cy,  cz, 0.f, -cx,  -cy, cx, 0.f};
            float K2K2[9];
            for (int i = 0; i < 3; ++i)
                for (int j = 0; j < 3; ++j) {
                    float s2 = 0.f;
                    for (int l = 0; l < 3; ++l) s2 += K2[i * 3 + l] * K2[l * 3 + j];
                    K2K2[i * 3 + j] = s2;
                }
            for (int i = 0; i < 9; ++i) {
                float I = (i == 0 || i == 4 || i == 8) ? 1.f : 0.f;
                R[i] = I + 2.f * K2K2[i];
            }
        } else if (dot > 0.f) {
            for (int i = 0; i < 9; ++i) R[i] = (i == 0 || i == 4 || i == 8) ? 1.f : 0.f;
        }
    }
    float ms0 = sums[0] / (float)NPTS, ms1 = sums[1] / (float)NPTS, ms2 = sums[2] / (float)NPTS;
    float mt0 = sums[3] / (float)NPTS, mt1 = sums[4] / (float)NPTS, mt2 = sums[5] / (float)NPTS;
    for (int i = 0; i < 9; ++i) R_out[i] = R[i];
    t_out[0] = mt0 - (R[0] * ms0 + R[1] * ms1 + R[2] * ms2);
    t_out[1] = mt1 - (R[3] * ms0 + R[4] * ms1 + R[5] * ms2);
    t_out[2] = mt2 - (R[6] * ms0 + R[7] * ms1 + R[8] * ms2);
}

// ============================================================================
// K0: fused per-batch setup. Grid NB x 1024 thr. Body == mega's P0, which
// ran bit-exact in R7. Mean accumulation on tid<256 with guarded work and
// FULL-block __syncthreads (R4 lesson: never raw s_barrier in a branch).
// ============================================================================
__global__ void k0_setup(const float* __restrict__ src, const float* __restrict__ tgt,
                         const float* __restrict__ src_n, const float* __restrict__ tgt_n,
                         const float* __restrict__ g_p, const float* __restrict__ g_q,
                         float4* __restrict__ p4, float4* __restrict__ q4,
                         float4* __restrict__ snr4, float4* __restrict__ tn4) {
    const int b = blockIdx.x;
    const int tid = threadIdx.x;
    const float* S  = src   + (size_t)b * 3 * NPTS;
    const float* T  = tgt   + (size_t)b * 3 * NPTS;
    const float* SN = src_n + (size_t)b * 3 * NPTS;
    const float* TN = tgt_n + (size_t)b * 3 * NPTS;

    __shared__ float red[256];
    __shared__ float sums[6];
    __shared__ float Rg[9], tc[3];

    float acc[6] = {0.f, 0.f, 0.f, 0.f, 0.f, 0.f};
    if (tid < 256) {
        for (int n = tid; n < NPTS; n += 256) {
            acc[0] += S[n]; acc[1] += S[NPTS + n]; acc[2] += S[2 * NPTS + n];
            acc[3] += T[n]; acc[4] += T[NPTS + n]; acc[5] += T[2 * NPTS + n];
        }
    }
    for (int c = 0; c < 6; ++c) {
        if (tid < 256) red[tid] = acc[c];
        __syncthreads();
        for (int s = 128; s > 0; s >>= 1) {
            if (tid < s) red[tid] += red[tid + s];
            __syncthreads();
        }
        if (tid == 0) sums[c] = red[0];
        __syncthreads();
    }

    if (tid == 0) gravity_align_rt(g_p, g_q, sums, b, Rg, tc);
    __syncthreads();

    const float R0 = Rg[0], R1 = Rg[1], R2 = Rg[2];
    const float R3 = Rg[3], R4 = Rg[4], R5 = Rg[5];
    const float R6 = Rg[6], R7 = Rg[7], R8 = Rg[8];
    const float t0 = tc[0], t1 = tc[1], t2 = tc[2];

    for (int n = tid; n < NPTS; n += 1024) {
        float s0 = S[n], s1 = S[NPTS + n], s2 = S[2 * NPTS + n];
        float p0 = R0 * s0 + R1 * s1 + R2 * s2 + t0;
        float p1 = R3 * s0 + R4 * s1 + R5 * s2 + t1;
        float p2 = R6 * s0 + R7 * s1 + R8 * s2 + t2;
        p4[b * NPTS + n] = make_float4(p0, p1, p2, p0 * p0 + p1 * p1 + p2 * p2);

        float q0 = T[n], q1 = T[NPTS + n], q2 = T[2 * NPTS + n];
        q4[b * NPTS + n] = make_float4(q0, q1, q2, q0 * q0 + q1 * q1 + q2 * q2);

        float a0 = SN[n], a1 = SN[NPTS + n], a2 = SN[2 * NPTS + n];
        snr4[b * NPTS + n] = make_float4(R0 * a0 + R1 * a1 + R2 * a2,
                                         R3 * a0 + R4 * a1 + R5 * a2,
                                         R6 * a0 + R7 * a1 + R8 * a2, 0.f);
        float c0 = TN[n], c1 = TN[NPTS + n], c2 = TN[2 * NPTS + n];
        tn4[b * NPTS + n] = make_float4(c0, c1, c2, 0.f);
    }
}

// ============================================================================
// K1: NN both directions, V=2 own-points per lane.
// Grid (32, NB, 2) = 256 blocks (1/CU), 1024 thr. Each block owns 128
// points (lane handles n0 and n0+64); each broadcast ds_read of q feeds 2
// score evals -> LDS read traffic halved vs R5. Scan order per point is
// unchanged (16 stripes x 256 m ascending; strict >; stripe-order combine)
// so argmin stays bit-exact.
// ============================================================================
__global__ void k1_nn(const float4* __restrict__ p4, const float4* __restrict__ q4,
                      float* __restrict__ nnp, int* __restrict__ idxp,
                      float* __restrict__ nnq, int* __restrict__ idxq) {
    const int b = blockIdx.y;
    const int z = blockIdx.z;
    const float4* own = z ? q4 : p4;
    const float4* oth = z ? p4 : q4;
    float* nn = z ? nnq : nnp;
    int* idx = z ? idxq : idxp;

    __shared__ float4 stage[NPTS];  // 64 KB
    const int tid = threadIdx.x;
    for (int i = tid; i < NPTS; i += 1024) {
        float4 v = oth[b * NPTS + i];
        v.w *= -0.5f;
        stage[i] = v;
    }

    const int nl = tid & 63;
    const int stripe = tid >> 6;          // 0..15, each scans 256 points
    const int n0 = blockIdx.x * 128 + nl; // point A; point B = n0+64
    const float4 pA = own[b * NPTS + n0];
    const float4 pB = own[b * NPTS + n0 + 64];
    __syncthreads();

    const int m0 = stripe << 8;
    float bestA = -3.4e38f, bestB = -3.4e38f;
    int biA = m0, biB = m0;
    #pragma unroll 8
    for (int m = m0; m < m0 + 256; ++m) {
        float4 q = stage[m];
        float sA = fmaf(pA.x, q.x, fmaf(pA.y, q.y, fmaf(pA.z, q.z, q.w)));
        float sB = fmaf(pB.x, q.x, fmaf(pB.y, q.y, fmaf(pB.z, q.z, q.w)));
        if (sA > bestA) { bestA = sA; biA = m; }
        if (sB > bestB) { bestB = sB; biB = m; }
    }
    __syncthreads();

    // combine in stage LDS: 2x1024 floats + 2x1024 ints (16 KB <= 64 KB)
    float* combd = (float*)stage;
    int* combi = (int*)(combd + 2048);
    combd[tid] = bestA;
    combd[1024 + tid] = bestB;
    combi[tid] = biA;
    combi[1024 + tid] = biB;
    __syncthreads();
    if (stripe == 0) {
        for (int s2 = 1; s2 < 16; ++s2) {
            float dA = combd[s2 * 64 + nl];
            int iA = combi[s2 * 64 + nl];
            if (dA > bestA) { bestA = dA; biA = iA; }   // ties: lower stripe wins
            float dB = combd[1024 + s2 * 64 + nl];
            int iB = combi[1024 + s2 * 64 + nl];
            if (dB > bestB) { bestB = dB; biB = iB; }
        }
        float dA = fmaf(-2.0f, bestA, pA.w);
        nn[b * NPTS + n0] = sqrtf(fmaxf(dA, 0.f) + EPSF);
        idx[b * NPTS + n0] = biA;
        float dB = fmaf(-2.0f, bestB, pB.w);
        nn[b * NPTS + n0 + 64] = sqrtf(fmaxf(dB, 0.f) + EPSF);
        idx[b * NPTS + n0 + 64] = biB;
    }
}

// ============================================================================
// KC: fused median (exact MSB radix-select) + incidence weights.
// Grid (NB, 2), 1024 thr. Each thread holds 4 nn values in registers.
// Lower median sorted[2047]: all values are positive floats (sqrt(x)+eps),
// so unsigned bit order == numeric order. 31 bit-iterations, each counts
// candidates matching the running prefix with current bit 0; all threads
// replicate identical rank/prefix updates -> deterministic, returns the
// BITWISE sorted[2047] value (ties value-identical). Then each thread
// computes its 4 weights (verbatim R5 k3 arithmetic).
// ============================================================================
__global__ void kc_tau_w(const float* __restrict__ nnp, const float* __restrict__ nnq,
                         const float4* __restrict__ snr4, const float4* __restrict__ tn4,
                         const int* __restrict__ idxp, const int* __restrict__ idxq,
                         const float* __restrict__ g_q, const float* __restrict__ k_p,
                         const float* __restrict__ k_q, float* __restrict__ out) {
    const int b = blockIdx.x;
    const int z = blockIdx.y;          // side: 0 -> p, 1 -> q
    const int tid = threadIdx.x;
    const float* a = (z ? nnq : nnp) + b * NPTS;

    // 4 values per thread, coalesced
    unsigned int v[4];
    float vf[4];
    #pragma unroll
    for (int j = 0; j < 4; ++j) {
        float x = a[tid + j * 1024];
        vf[j] = x;
        v[j] = __float_as_uint(x);
    }

    __shared__ int wsum[16];
    __shared__ int tot_s;

    unsigned int prefix = 0u;
    int rank = 2047;
    const int wid = tid >> 6;
    const int lane = tid & 63;

    for (int bit = 30; bit >= 0; --bit) {
        const unsigned int hi_mask = ~((1u << (bit + 1)) - 1u);  // bits above 'bit'
        int c = 0;
        #pragma unroll
        for (int j = 0; j < 4; ++j) {
            bool match = (v[j] & hi_mask) == prefix;
            bool bz = ((v[j] >> bit) & 1u) == 0u;
            c += (match && bz) ? 1 : 0;
        }
        // wave reduce (64 lanes)
        #pragma unroll
        for (int o = 32; o > 0; o >>= 1) c += __shfl_xor(c, o, 64);
        if (lane == 0) wsum[wid] = c;
        __syncthreads();
        if (tid == 0) {
            int t = 0;
            #pragma unroll
            for (int i = 0; i < 16; ++i) t += wsum[i];
            tot_s = t;
        }
        __syncthreads();
        const int tot = tot_s;
        if (rank < tot) {
            // target bit = 0; prefix unchanged
        } else {
            rank -= tot;
            prefix |= (1u << bit);
        }
        __syncthreads();   // wsum/tot_s reused next iteration
    }
    const float tauv = 3.0f * __uint_as_float(prefix);

    // ---- weights (verbatim R5 k3 arithmetic) ----
    const float gx = g_q[3 * b + 0], gy = g_q[3 * b + 1], gz = g_q[3 * b + 2];
    const float kp = k_p[b], kq = k_q[b];
    const float keff = kp * kq / (kp + kq + EPSF);

    #pragma unroll
    for (int j = 0; j < 4; ++j) {
        const int n = tid + j * 1024;
        float w;
        if (z == 0) {
            float4 sn = snr4[b * NPTS + n];
            float inc = sn.x * gx + sn.y * gy + sn.z * gz;
            int jj = idxp[b * NPTS + n];
            float4 tn = tn4[b * NPTS + jj];
            float incr = tn.x * gx + tn.y * gy + tn.z * gz;
            float diff = inc - incr;
            float arg = 9.0f - keff * diff * diff;
            float sig = 1.f / (1.f + expf(-arg));
            float geom = (vf[j] <= tauv) ? 1.f : 0.f;
            w = sig * geom;
        } else {
            float4 tn = tn4[b * NPTS + n];
            float inc = tn.x * gx + tn.y * gy + tn.z * gz;
            int jj = idxq[b * NPTS + n];
            float4 sn = snr4[b * NPTS + jj];
            float incr = sn.x * gx + sn.y * gy + sn.z * gz;
            float diff = inc - incr;
            float arg = 9.0f - keff * diff * diff;
            float sig = 1.f / (1.f + expf(-arg));
            float geom = (vf[j] <= tauv) ? 1.f : 0.f;
            w = sig * geom;
        }
        out[z * (NB * NPTS) + b * NPTS + n] = w;
    }
}

extern "C" void kernel_launch(void* const* d_in, const int* in_sizes, int n_in,
                              void* d_out, int out_size, void* d_ws, size_t ws_size,
                              hipStream_t stream) {
    const float* src   = (const float*)d_in[0];
    const float* tgt   = (const float*)d_in[1];
    const float* src_n = (const float*)d_in[2];
    const float* tgt_n = (const float*)d_in[3];
    const float* g_p   = (const float*)d_in[4];
    const float* k_p   = (const float*)d_in[5];
    const float* g_q   = (const float*)d_in[6];
    const float* k_q   = (const float*)d_in[7];
    float* out = (float*)d_out;

    const int BN = NB * NPTS;
    float4* p4   = (float4*)d_ws;
    float4* q4   = p4 + BN;
    float4* snr4 = q4 + BN;
    float4* tn4  = snr4 + BN;
    float* nnp = (float*)(tn4 + BN);
    float* nnq = nnp + BN;
    int* idxp = (int*)(nnq + BN);
    int* idxq = idxp + BN;

    k0_setup<<<dim3(NB), dim3(1024), 0, stream>>>(src, tgt, src_n, tgt_n, g_p, g_q,
                                                  p4, q4, snr4, tn4);
    k1_nn<<<dim3(NPTS / 128, NB, 2), dim3(1024), 0, stream>>>(p4, q4, nnp, idxp, nnq, idxq);
    kc_tau_w<<<dim3(NB, 2), dim3(1024), 0, stream>>>(nnp, nnq, snr4, tn4, idxp, idxq,
                                                     g_q, k_p, k_q, out);
}

// Round 9
// 53.279 us; speedup vs baseline: 10.1125x; 1.2683x over previous
//
#include <hip/hip_runtime.h>
#include <math.h>

#define NPTS 4096
#define NB 4
#define EPSF 1e-6f

// ============================================================================
// gravity_align + t_center (exact reference arithmetic; bit-exact R1-R8).
// ============================================================================
__device__ __forceinline__ void gravity_align_rt(
    const float* __restrict__ g_p, const float* __restrict__ g_q,
    const float* sums, int b, float* R_out, float* t_out) {
    float gpx = g_p[3 * b + 0], gpy = g_p[3 * b + 1], gpz = g_p[3 * b + 2];
    float gqx = g_q[3 * b + 0], gqy = g_q[3 * b + 1], gqz = g_q[3 * b + 2];
    float nu = sqrtf(gpx * gpx + gpy * gpy + gpz * gpz);
    float du = fmaxf(nu, EPSF);
    float ux = gpx / du, uy = gpy / du, uz = gpz / du;
    float nv = sqrtf(gqx * gqx + gqy * gqy + gqz * gqz);
    float dv = fmaxf(nv, EPSF);
    float vx = gqx / dv, vy = gqy / dv, vz = gqz / dv;

    float ax = uy * vz - uz * vy;
    float ay = uz * vx - ux * vz;
    float az = ux * vy - uy * vx;
    float an = sqrtf(ax * ax + ay * ay + az * az);
    float dot = ux * vx + uy * vy + uz * vz;
    dot = fminf(1.0f, fmaxf(-1.0f, dot));
    bool parallel = (an < 1e-6f);

    float kx = ax / (an + EPSF), ky = ay / (an + EPSF), kz = az / (an + EPSF);
    float theta = acosf(dot);
    float st = sinf(theta), ct = cosf(theta);

    float K[9] = {0.f, -kz, ky,  kz, 0.f, -kx,  -ky, kx, 0.f};
    float KK[9];
    for (int i = 0; i < 3; ++i)
        for (int j = 0; j < 3; ++j) {
            float s2 = 0.f;
            for (int l = 0; l < 3; ++l) s2 += K[i * 3 + l] * K[l * 3 + j];
            KK[i * 3 + j] = s2;
        }
    float R[9];
    for (int i = 0; i < 9; ++i) {
        float I = (i == 0 || i == 4 || i == 8) ? 1.f : 0.f;
        R[i] = I + st * K[i] + (1.f - ct) * KK[i];
    }
    if (parallel) {
        if (dot < 0.f) {
            float bx, by, bz;
            if (fabsf(ux) < 0.9f) { bx = 1.f; by = 0.f; bz = 0.f; }
            else                  { bx = 0.f; by = 1.f; bz = 0.f; }
            float cx = uy * bz - uz * by;
            float cy = uz * bx - ux * bz;
            float cz = ux * by - uy * bx;
            float cn = sqrtf(cx * cx + cy * cy + cz * cz);
            float cd = fmaxf(cn, EPSF);
            cx /= cd; cy /= cd; cz /= cd;
            float K2[9] = {0.f, -cz, cy,  cz, 0.f, -cx,  -cy, cx, 0.f};
            float K2K2[9];
            for (int i = 0; i < 3; ++i)
                for (int j = 0; j < 3; ++j) {
                    float s2 = 0.f;
                    for (int l = 0; l < 3; ++l) s2 += K2[i * 3 + l] * K2[l * 3 + j];
                    K2K2[i * 3 + j] = s2;
                }
            for (int i = 0; i < 9; ++i) {
                float I = (i == 0 || i == 4 || i == 8) ? 1.f : 0.f;
                R[i] = I + 2.f * K2K2[i];
            }
        } else if (dot > 0.f) {
            for (int i = 0; i < 9; ++i) R[i] = (i == 0 || i == 4 || i == 8) ? 1.f : 0.f;
        }
    }
    float ms0 = sums[0] / (float)NPTS, ms1 = sums[1] / (float)NPTS, ms2 = sums[2] / (float)NPTS;
    float mt0 = sums[3] / (float)NPTS, mt1 = sums[4] / (float)NPTS, mt2 = sums[5] / (float)NPTS;
    for (int i = 0; i < 9; ++i) R_out[i] = R[i];
    t_out[0] = mt0 - (R[0] * ms0 + R[1] * ms1 + R[2] * ms2);
    t_out[1] = mt1 - (R[3] * ms0 + R[4] * ms1 + R[5] * ms2);
    t_out[2] = mt2 - (R[6] * ms0 + R[7] * ms1 + R[8] * ms2);
}

// ============================================================================
// K0: fused per-batch setup (verbatim R8, proven). Grid NB x 1024 thr.
// ============================================================================
__global__ void k0_setup(const float* __restrict__ src, const float* __restrict__ tgt,
                         const float* __restrict__ src_n, const float* __restrict__ tgt_n,
                         const float* __restrict__ g_p, const float* __restrict__ g_q,
                         float4* __restrict__ p4, float4* __restrict__ q4,
                         float4* __restrict__ snr4, float4* __restrict__ tn4) {
    const int b = blockIdx.x;
    const int tid = threadIdx.x;
    const float* S  = src   + (size_t)b * 3 * NPTS;
    const float* T  = tgt   + (size_t)b * 3 * NPTS;
    const float* SN = src_n + (size_t)b * 3 * NPTS;
    const float* TN = tgt_n + (size_t)b * 3 * NPTS;

    __shared__ float red[256];
    __shared__ float sums[6];
    __shared__ float Rg[9], tc[3];

    float acc[6] = {0.f, 0.f, 0.f, 0.f, 0.f, 0.f};
    if (tid < 256) {
        for (int n = tid; n < NPTS; n += 256) {
            acc[0] += S[n]; acc[1] += S[NPTS + n]; acc[2] += S[2 * NPTS + n];
            acc[3] += T[n]; acc[4] += T[NPTS + n]; acc[5] += T[2 * NPTS + n];
        }
    }
    for (int c = 0; c < 6; ++c) {
        if (tid < 256) red[tid] = acc[c];
        __syncthreads();
        for (int s = 128; s > 0; s >>= 1) {
            if (tid < s) red[tid] += red[tid + s];
            __syncthreads();
        }
        if (tid == 0) sums[c] = red[0];
        __syncthreads();
    }

    if (tid == 0) gravity_align_rt(g_p, g_q, sums, b, Rg, tc);
    __syncthreads();

    const float R0 = Rg[0], R1 = Rg[1], R2 = Rg[2];
    const float R3 = Rg[3], R4 = Rg[4], R5 = Rg[5];
    const float R6 = Rg[6], R7 = Rg[7], R8 = Rg[8];
    const float t0 = tc[0], t1 = tc[1], t2 = tc[2];

    for (int n = tid; n < NPTS; n += 1024) {
        float s0 = S[n], s1 = S[NPTS + n], s2 = S[2 * NPTS + n];
        float p0 = R0 * s0 + R1 * s1 + R2 * s2 + t0;
        float p1 = R3 * s0 + R4 * s1 + R5 * s2 + t1;
        float p2 = R6 * s0 + R7 * s1 + R8 * s2 + t2;
        p4[b * NPTS + n] = make_float4(p0, p1, p2, p0 * p0 + p1 * p1 + p2 * p2);

        float q0 = T[n], q1 = T[NPTS + n], q2 = T[2 * NPTS + n];
        q4[b * NPTS + n] = make_float4(q0, q1, q2, q0 * q0 + q1 * q1 + q2 * q2);

        float a0 = SN[n], a1 = SN[NPTS + n], a2 = SN[2 * NPTS + n];
        snr4[b * NPTS + n] = make_float4(R0 * a0 + R1 * a1 + R2 * a2,
                                         R3 * a0 + R4 * a1 + R5 * a2,
                                         R6 * a0 + R7 * a1 + R8 * a2, 0.f);
        float c0 = TN[n], c1 = TN[NPTS + n], c2 = TN[2 * NPTS + n];
        tn4[b * NPTS + n] = make_float4(c0, c1, c2, 0.f);
    }
}

// ============================================================================
// K1: NN both directions — VERBATIM R5 config (fastest proven: 512 blocks
// = 2/CU = 32 waves/CU, 64 own-points/block, 16 stripes x 256 ascending).
// R8 lesson: V=2 reuse halves LDS reads but not VALU, and halving
// occupancy was a net loss. Do not re-apply.
// ============================================================================
__global__ void k1_nn(const float4* __restrict__ p4, const float4* __restrict__ q4,
                      float* __restrict__ nnp, int* __restrict__ idxp,
                      float* __restrict__ nnq, int* __restrict__ idxq) {
    const int b = blockIdx.y;
    const int z = blockIdx.z;
    const float4* own = z ? q4 : p4;
    const float4* oth = z ? p4 : q4;
    float* nn = z ? nnq : nnp;
    int* idx = z ? idxq : idxp;

    __shared__ float4 stage[NPTS];  // 64 KB
    const int tid = threadIdx.x;
    for (int i = tid; i < NPTS; i += 1024) {
        float4 v = oth[b * NPTS + i];
        v.w *= -0.5f;
        stage[i] = v;
    }

    const int nl = tid & 63;
    const int stripe = tid >> 6;          // 0..15, each scans 256 points
    const int n = blockIdx.x * 64 + nl;
    const float4 p = own[b * NPTS + n];
    __syncthreads();

    const int m0 = stripe << 8;
    float best = -3.4e38f;
    int bi = m0;
    #pragma unroll 8
    for (int m = m0; m < m0 + 256; ++m) {
        float4 q = stage[m];
        float s = fmaf(p.x, q.x, fmaf(p.y, q.y, fmaf(p.z, q.z, q.w)));
        if (s > best) { best = s; bi = m; }
    }
    __syncthreads();

    float* combd = (float*)stage;
    int* combi = (int*)(combd + 1024);
    combd[tid] = best;
    combi[tid] = bi;
    __syncthreads();
    if (stripe == 0) {
        for (int s2 = 1; s2 < 16; ++s2) {
            float d2 = combd[s2 * 64 + nl];
            int i2 = combi[s2 * 64 + nl];
            if (d2 > best) { best = d2; bi = i2; }  // ties: lower m wins
        }
        float d = fmaf(-2.0f, best, p.w);
        nn[b * NPTS + n] = sqrtf(fmaxf(d, 0.f) + EPSF);
        idx[b * NPTS + n] = bi;
    }
}

// ============================================================================
// KC: fused exact median select + incidence weights. Grid (NB, 2), 1024 thr.
// Median sorted[2047] via 4-pass 8-bit-digit radix select on the positive-
// float bit patterns (uint order == float order). Same rank/prefix recursion
// as R8's bit-serial version (proven bit-exact) but 8 bits/pass:
//   - per-WAVE 256-bin LDS histograms (atomic contention bounded to the
//     wave's own 256 values; no cross-wave conflicts)
//   - block combine (threads 0..255 sum the 16 copies)
//   - wave 0: 4-bins/lane shfl_up prefix scan picks the digit (unique
//     writer publishes digit + exclusive base)
// 16 block syncs total vs R8's ~62 (R8 lesson: block-wide sync count was
// the kc cost). Weights part verbatim R8 (proven).
// ============================================================================
__global__ void kc_tau_w(const float* __restrict__ nnp, const float* __restrict__ nnq,
                         const float4* __restrict__ snr4, const float4* __restrict__ tn4,
                         const int* __restrict__ idxp, const int* __restrict__ idxq,
                         const float* __restrict__ g_q, const float* __restrict__ k_p,
                         const float* __restrict__ k_q, float* __restrict__ out) {
    const int b = blockIdx.x;
    const int z = blockIdx.y;          // side: 0 -> p, 1 -> q
    const int tid = threadIdx.x;
    const int wid = tid >> 6;
    const int lane = tid & 63;
    const float* a = (z ? nnq : nnp) + b * NPTS;

    unsigned int v[4];
    float vf[4];
    #pragma unroll
    for (int j = 0; j < 4; ++j) {
        float x = a[tid + j * 1024];
        vf[j] = x;
        v[j] = __float_as_uint(x);   // positive floats: bit31 == 0
    }

    __shared__ int hist[16][256];    // per-wave histograms, 16 KB
    __shared__ int tot[256];
    __shared__ int digit_s, base_s;

    const int shifts[4]   = {23, 15, 7, 0};
    const unsigned him[4] = {0x00000000u, 0x7F800000u, 0x7FFF8000u, 0x7FFFFF80u};
    const unsigned dm[4]  = {0xFFu, 0xFFu, 0xFFu, 0x7Fu};

    unsigned int prefix = 0u;
    int rank = 2047;

    for (int p = 0; p < 4; ++p) {
        const int sh = shifts[p];
        const unsigned himask = him[p];
        const unsigned dmask = dm[p];

        for (int k2 = lane; k2 < 256; k2 += 64) hist[wid][k2] = 0;
        __syncthreads();

        #pragma unroll
        for (int j = 0; j < 4; ++j) {
            if ((v[j] & himask) == prefix)
                atomicAdd(&hist[wid][(v[j] >> sh) & dmask], 1);
        }
        __syncthreads();

        if (tid < 256) {
            int t = 0;
            #pragma unroll
            for (int w = 0; w < 16; ++w) t += hist[w][tid];
            tot[tid] = t;
        }
        __syncthreads();

        if (wid == 0) {
            // lane owns bins [4*lane, 4*lane+4)
            int c0 = tot[4 * lane + 0], c1 = tot[4 * lane + 1];
            int c2 = tot[4 * lane + 2], c3 = tot[4 * lane + 3];
            int s = c0 + c1 + c2 + c3;
            int incl = s;
            #pragma unroll
            for (int o = 1; o < 64; o <<= 1) {
                int t = __shfl_up(incl, o, 64);
                if (lane >= o) incl += t;
            }
            int base = incl - s;   // exclusive prefix of this lane's group
            int cs[4] = {c0, c1, c2, c3};
            #pragma unroll
            for (int k2 = 0; k2 < 4; ++k2) {
                if (cs[k2] > 0 && rank >= base && rank < base + cs[k2]) {
                    digit_s = 4 * lane + k2;   // unique writer
                    base_s = base;
                }
                base += cs[k2];
            }
        }
        __syncthreads();
        prefix |= ((unsigned)digit_s) << sh;
        rank -= base_s;
        __syncthreads();   // digit_s/base_s reused next pass
    }
    const float tauv = 3.0f * __uint_as_float(prefix);

    // ---- weights (verbatim R8, proven) ----
    const float gx = g_q[3 * b + 0], gy = g_q[3 * b + 1], gz = g_q[3 * b + 2];
    const float kp = k_p[b], kq = k_q[b];
    const float keff = kp * kq / (kp + kq + EPSF);

    #pragma unroll
    for (int j = 0; j < 4; ++j) {
        const int n = tid + j * 1024;
        float w;
        if (z == 0) {
            float4 sn = snr4[b * NPTS + n];
            float inc = sn.x * gx + sn.y * gy + sn.z * gz;
            int jj = idxp[b * NPTS + n];
            float4 tn = tn4[b * NPTS + jj];
            float incr = tn.x * gx + tn.y * gy + tn.z * gz;
            float diff = inc - incr;
            float arg = 9.0f - keff * diff * diff;
            float sig = 1.f / (1.f + expf(-arg));
            float geom = (vf[j] <= tauv) ? 1.f : 0.f;
            w = sig * geom;
        } else {
            float4 tn = tn4[b * NPTS + n];
            float inc = tn.x * gx + tn.y * gy + tn.z * gz;
            int jj = idxq[b * NPTS + n];
            float4 sn = snr4[b * NPTS + jj];
            float incr = sn.x * gx + sn.y * gy + sn.z * gz;
            float diff = inc - incr;
            float arg = 9.0f - keff * diff * diff;
            float sig = 1.f / (1.f + expf(-arg));
            float geom = (vf[j] <= tauv) ? 1.f : 0.f;
            w = sig * geom;
        }
        out[z * (NB * NPTS) + b * NPTS + n] = w;
    }
}

extern "C" void kernel_launch(void* const* d_in, const int* in_sizes, int n_in,
                              void* d_out, int out_size, void* d_ws, size_t ws_size,
                              hipStream_t stream) {
    const float* src   = (const float*)d_in[0];
    const float* tgt   = (const float*)d_in[1];
    const float* src_n = (const float*)d_in[2];
    const float* tgt_n = (const float*)d_in[3];
    const float* g_p   = (const float*)d_in[4];
    const float* k_p   = (const float*)d_in[5];
    const float* g_q   = (const float*)d_in[6];
    const float* k_q   = (const float*)d_in[7];
    float* out = (float*)d_out;

    const int BN = NB * NPTS;
    float4* p4   = (float4*)d_ws;
    float4* q4   = p4 + BN;
    float4* snr4 = q4 + BN;
    float4* tn4  = snr4 + BN;
    float* nnp = (float*)(tn4 + BN);
    float* nnq = nnp + BN;
    int* idxp = (int*)(nnq + BN);
    int* idxq = idxp + BN;

    k0_setup<<<dim3(NB), dim3(1024), 0, stream>>>(src, tgt, src_n, tgt_n, g_p, g_q,
                                                  p4, q4, snr4, tn4);
    k1_nn<<<dim3(NPTS / 64, NB, 2), dim3(1024), 0, stream>>>(p4, q4, nnp, idxp, nnq, idxq);
    kc_tau_w<<<dim3(NB, 2), dim3(1024), 0, stream>>>(nnp, nnq, snr4, tn4, idxp, idxq,
                                                     g_q, k_p, k_q, out);
}